// Round 5
// baseline (767.985 us; speedup 1.0000x reference)
//
#include <hip/hip_runtime.h>

// RetinaNet head via bf16 MFMA implicit-GEMM (16x16x32) — R6 structure.
// Activations: padded NHWC bf16 [plane][(H+2)(W+2)][256], zero borders.
// R6 = R1's proven sync structure (single-buffered LDS, 2 syncthreads/chunk,
// 2 blocks/CU, compiler-scheduled chunk body) with DOUBLE the per-wave acc
// tile: wave = 64co x 128px (8 rows x 16 cols), acc[4][8]. This halves LDS
// reads per FLOP (0.375 -> 0.229 ds_read_b128/MFMA), taking the CU-shared
// LDS read pipe (12 cyc/b128) off the critical path — the R2-R5 post-mortems
// showed scheduling was never the stall; LDS byte volume was.
// Block: 256 threads, 4 waves, tile 64co x 512px (32 rows x 16 cols,
// halo 34x18 = 612 slots). Per ci-chunk(32) per wave: 30 B + 36 A
// ds_read_b128 feed 288 MFMA. LDS: W 36864B + X 40960B = 77824B.
// W blob layout (R1's): [cb][chunk32][tap][q4][co64][8ci].
// X LDS layout: linear u = q*612 + r*18 + c slots of 16B (10 staging groups).

typedef __attribute__((ext_vector_type(8))) short short8;
typedef __attribute__((ext_vector_type(4))) float floatx4;

#define LVLTOT 14143  // sum of padded (H+2)(W+2) over 5 levels

__device__ __forceinline__ unsigned short f2bf(float f) {
  unsigned int u = __float_as_uint(f);
  unsigned int r = (u + 0x7fffu + ((u >> 16) & 1u)) >> 16;
  return (unsigned short)r;
}

__device__ __forceinline__ void gload_lds16(const void* g, void* l) {
  __builtin_amdgcn_global_load_lds(
      (const __attribute__((address_space(1))) unsigned int*)g,
      (__attribute__((address_space(3))) unsigned int*)l, 16, 0, 0);
}

// ================= fused prep: xprep + wprep + border zero =================
// blocks [0,1090): xprep strips; [1090,3970): wprep (one co per block);
// [3970,4770): border zeroing (exact enumeration).
struct PrepArgs {
  const float* f[5];
  const float* w[10];
  unsigned short* wdst[10];
  int wblk_off[11];
  int cout[10];
  unsigned short* x0;
  unsigned short* bufA;
  unsigned short* bufB;
};

__global__ __launch_bounds__(256) void prep(PrepArgs A) {
  static const int Ht[5] = {100, 50, 25, 13, 7};
  static const int Wpt[5] = {102, 52, 27, 15, 9};
  static const int LOFFt[5] = {0, 10404, 13108, 13837, 14062};
  __shared__ float ts[32][33];
  const int bid = blockIdx.x;
  const int t = threadIdx.x;

  if (bid < 1090) {
    // ---- xprep: one 32-px row-strip, all 256 ch, one n ----
    int sid = bid % 545, n = bid / 545;
    int l, h, wb;
    if (sid < 400)      { l = 0; h = sid >> 2; wb = sid & 3; }
    else if (sid < 500) { l = 1; h = (sid - 400) >> 1; wb = (sid - 400) & 1; }
    else if (sid < 525) { l = 2; h = sid - 500; wb = 0; }
    else if (sid < 538) { l = 3; h = sid - 525; wb = 0; }
    else                { l = 4; h = sid - 538; wb = 0; }
    const float* f = A.f[l];
    int H = Ht[l], W = H, Wp = Wpt[l], loff = LOFFt[l];
    int w0 = wb * 32;
    for (int s = 0; s < 8; s++) {
      int ch0 = s * 32;
      __syncthreads();
#pragma unroll
      for (int r4 = 0; r4 < 4; r4++) {
        int ch = ch0 + (t >> 5) + r4 * 8;
        int px = w0 + (t & 31);
        float v = 0.f;
        if (px < W) v = f[(((size_t)n * 256 + ch) * H + h) * W + px];
        ts[(t >> 5) + r4 * 8][t & 31] = v;
      }
      __syncthreads();
      int pxl = t >> 3, c4 = t & 7;
      if (w0 + pxl < W) {
        unsigned short pk[4];
#pragma unroll
        for (int k = 0; k < 4; k++) pk[k] = f2bf(ts[c4 * 4 + k][pxl]);
        *(unsigned long long*)(A.x0 +
            ((size_t)n * LVLTOT + loff + (size_t)(h + 1) * Wp + (w0 + pxl + 1)) *
                256 + ch0 + c4 * 4) = *(unsigned long long*)pk;
      }
    }
    return;
  }

  if (bid < 3970) {
    // ---- wprep: block = one padded co of one tensor; thread = ci ----
    // Layout: [cb][chunk(ci>>5)][tap][qd][co64][8]
    int b2 = bid - 1090;
    int tix = 0;
    while (b2 >= A.wblk_off[tix + 1]) tix++;
    int co = b2 - A.wblk_off[tix];
    int ci = t;
    bool valid = co < A.cout[tix];
    const float* w = A.w[tix];
    unsigned short* dst = A.wdst[tix];
    int cb = co >> 6, col = co & 63, chk = ci >> 5, qd = (ci >> 3) & 3, j = ci & 7;
#pragma unroll
    for (int tap = 0; tap < 9; tap++) {
      float v = valid ? w[((size_t)co * 256 + ci) * 9 + tap] : 0.f;
      dst[((((size_t)(cb * 8 + chk) * 9 + tap) * 4 + qd) * 64 + col) * 8 + j] =
          f2bf(v);
    }
    return;
  }

  // ---- border zero: items = 800 border px x 32 octs per plane ----
  {
    static const int BCUM[6] = {0, 404, 608, 712, 768, 800};
    int b3 = bid - 3970;             // [0,800): plane = b3/100
    int plane = b3 / 100;
    int item = (b3 % 100) * 256 + t; // [0,25600)
    int pxi = item >> 5, oct = item & 31;
    if (pxi >= 800) return;
    int l = 0;
    while (pxi >= BCUM[l + 1]) l++;
    int j = pxi - BCUM[l];
    int Wp = Wpt[l];
    int r, c;
    if (j < Wp)            { r = 0; c = j; }
    else if (j < 2 * Wp)   { r = Wp - 1; c = j - Wp; }
    else { int k = j - 2 * Wp; r = 1 + (k >> 1); c = (k & 1) ? Wp - 1 : 0; }
    size_t px = (size_t)LOFFt[l] + (size_t)r * Wp + c;
    unsigned short* base = (plane < 4)
                               ? (A.bufA + (size_t)plane * LVLTOT * 256)
                               : (A.bufB + (size_t)(plane - 4) * LVLTOT * 256);
    floatx4 z;
    z[0] = z[1] = z[2] = z[3] = 0.f;
    *(floatx4*)(base + px * 256 + oct * 8) = z;
  }
}

// ---- tile decode (40 tiles of 32 rows x 16 cols over 5 levels) ----
__device__ __forceinline__ void decode_tile(int tile, int& l, int& h0, int& w0,
                                            int& H, int& W, int& Wp, int& loff) {
  const int Ht[5] = {100, 50, 25, 13, 7};
  const int Wpt[5] = {102, 52, 27, 15, 9};
  const int TXt[5] = {7, 4, 2, 1, 1};  // col-tiles of 16
  const int LOFFt[5] = {0, 10404, 13108, 13837, 14062};
  int tloc;
  if (tile < 28) { l = 0; tloc = tile; }
  else if (tile < 36) { l = 1; tloc = tile - 28; }
  else if (tile < 38) { l = 2; tloc = tile - 36; }
  else if (tile < 39) { l = 3; tloc = tile - 38; }
  else { l = 4; tloc = 0; }
  H = Ht[l]; W = H; Wp = Wpt[l]; loff = LOFFt[l];
  int ty = tloc / TXt[l], tx = tloc - ty * TXt[l];
  h0 = ty * 32; w0 = tx * 16;
}

// ---- K-loop body (needs: t, lane, wv, q, n16, h0, w0, Hpad, Wp,
//      lds_w, lds_x, acc[4][8]) ----
// X staging: linear u = k*256 + t -> (q = u/612, slot = u%612, r = slot/18,
// c = slot%18); dest is wave-uniform base (k*256+wv*64)*16B + lane*16B (HW).
#define CONV_MAIN_LOOP(INP, WBLOB, CB)                                         \
  {                                                                            \
    int xsrc[10];                                                              \
    _Pragma("unroll") for (int k = 0; k < 10; k++) {                           \
      int u = k * 256 + t;                                                     \
      if (u > 2447) u = 2447;                                                  \
      int qq = u / 612, sl = u - qq * 612;                                     \
      int r_ = sl / 18, c_ = sl - r_ * 18;                                     \
      int hh = h0 + r_; if (hh > Hpad - 1) hh = Hpad - 1;                      \
      int ww = w0 + c_; if (ww > Wp - 1) ww = Wp - 1;                          \
      xsrc[k] = (hh * Wp + ww) * 256 + qq * 8;                                 \
    }                                                                          \
    _Pragma("unroll 1") for (int ch = 0; ch < 8; ch++) {                       \
      if (ch) __syncthreads();                                                 \
      const unsigned short* wsrc = (WBLOB) + ((size_t)((CB)*8 + ch)) * 18432;  \
      _Pragma("unroll") for (int i = 0; i < 9; i++)                            \
        gload_lds16(wsrc + i * 2048 + wv * 512 + lane * 8,                     \
                    lds_w + i * 2048 + wv * 512);                              \
      _Pragma("unroll") for (int k = 0; k < 10; k++)                           \
        gload_lds16((INP) + xsrc[k] + ch * 32,                                 \
                    lds_x + (size_t)(k * 256 + wv * 64) * 8);                  \
      __syncthreads();                                                         \
      const short8* xw = (const short8*)lds_w;                                 \
      const short8* xx = (const short8*)lds_x;                                 \
      _Pragma("unroll") for (int tdx = 0; tdx < 3; tdx++) {                    \
        short8 bfr[10];                                                        \
        _Pragma("unroll") for (int rb = 0; rb < 10; rb++)                      \
          bfr[rb] = xx[q * 612 + (wv * 8 + rb) * 18 + n16 + tdx];              \
        _Pragma("unroll") for (int tdy = 0; tdy < 3; tdy++) {                  \
          const int tap = tdy * 3 + tdx;                                       \
          _Pragma("unroll") for (int cA = 0; cA < 4; cA++) {                   \
            short8 afr = xw[(tap * 4 + q) * 64 + cA * 16 + n16];               \
            _Pragma("unroll") for (int rr = 0; rr < 8; rr++)                   \
              acc[cA][rr] = __builtin_amdgcn_mfma_f32_16x16x32_bf16(           \
                  afr, bfr[rr + tdy], acc[cA][rr], 0, 0, 0);                   \
          }                                                                    \
        }                                                                      \
      }                                                                        \
    }                                                                          \
  }

// ---- tower conv layer (bf16 in -> bf16 out, +bias, ReLU) ----
__global__ __launch_bounds__(256, 2) void conv_tower_mfma(
    const unsigned short* __restrict__ xin, unsigned short* __restrict__ xout,
    const unsigned short* __restrict__ wblob_cls,
    const unsigned short* __restrict__ wblob_box,
    const float* __restrict__ bias_cls, const float* __restrict__ bias_box,
    int in_n_stride, int in_tw_stride) {
  __shared__ __align__(16) unsigned short lds_w[18432];
  __shared__ __align__(16) unsigned short lds_x[20480];
  const int t = threadIdx.x, lane = t & 63, wv = t >> 6;
  const int q = lane >> 4, n16 = lane & 15;
  int l, h0, w0, H, W, Wp, loff;
  decode_tile(blockIdx.x, l, h0, w0, H, W, Wp, loff);
  const int Hpad = H + 2;
  const int cb = blockIdx.y;
  const int n = blockIdx.z >> 1, tw = blockIdx.z & 1;
  const unsigned short* wblob = tw ? wblob_box : wblob_cls;
  const float* bias = tw ? bias_box : bias_cls;
  const unsigned short* inp =
      xin + ((size_t)n * in_n_stride + (size_t)tw * in_tw_stride + loff) * 256;
  unsigned short* outp = xout + ((size_t)(n * 2 + tw) * LVLTOT + loff) * 256;

  floatx4 acc[4][8];
#pragma unroll
  for (int i = 0; i < 4; i++)
#pragma unroll
    for (int jj = 0; jj < 8; jj++) acc[i][jj] = (floatx4){0.f, 0.f, 0.f, 0.f};

  CONV_MAIN_LOOP(inp, wblob, cb)

  // epilogue: +bias, relu, bf16, store 4 consecutive channels (8B) per lane
#pragma unroll
  for (int cA = 0; cA < 4; cA++) {
    floatx4 bb = *(const floatx4*)(bias + cb * 64 + cA * 16 + q * 4);
#pragma unroll
    for (int rr = 0; rr < 8; rr++) {
      int h = h0 + wv * 8 + rr;
      int w_ = w0 + n16;
      if (h < H && w_ < W) {
        unsigned short pk[4];
#pragma unroll
        for (int rg = 0; rg < 4; rg++)
          pk[rg] = f2bf(fmaxf(acc[cA][rr][rg] + bb[rg], 0.f));
        size_t base =
            ((size_t)(h + 1) * Wp + (w_ + 1)) * 256 + cb * 64 + cA * 16 + q * 4;
        *(unsigned long long*)(outp + base) = *(unsigned long long*)pk;
      }
    }
  }
}

// ---- merged final conv (y<12: cls cb=y; y==12: box), permuted fp32 out ----
__global__ __launch_bounds__(256, 2) void conv_final_mfma(
    const unsigned short* __restrict__ xin, float* __restrict__ out,
    const unsigned short* __restrict__ wblob_cls,
    const unsigned short* __restrict__ wblob_box,
    const float* __restrict__ bias_cls, const float* __restrict__ bias_box) {
  __shared__ __align__(16) unsigned short lds_w[18432];
  __shared__ __align__(16) unsigned short lds_x[20480];
  const int t = threadIdx.x, lane = t & 63, wv = t >> 6;
  const int q = lane >> 4, n16 = lane & 15;
  int l, h0, w0, H, W, Wp, loff;
  decode_tile(blockIdx.x, l, h0, w0, H, W, Wp, loff);
  const int Hpad = H + 2;
  const int yb = blockIdx.y;
  const bool is_cls = yb < 12;
  const int cb = is_cls ? yb : 0;
  const int tw = is_cls ? 0 : 1;
  const int Cout = is_cls ? 720 : 36;
  const unsigned short* wblob = is_cls ? wblob_cls : wblob_box;
  const float* bias = is_cls ? bias_cls : bias_box;
  const int n = blockIdx.z;
  const int RB[5] = {0, 90000, 112500, 118125, 119646};
  const unsigned short* inp = xin + ((size_t)(n * 2 + tw) * LVLTOT + loff) * 256;

  floatx4 acc[4][8];
#pragma unroll
  for (int i = 0; i < 4; i++)
#pragma unroll
    for (int jj = 0; jj < 8; jj++) acc[i][jj] = (floatx4){0.f, 0.f, 0.f, 0.f};

  CONV_MAIN_LOOP(inp, wblob, cb)

#pragma unroll
  for (int cA = 0; cA < 4; cA++) {
    int co0 = cb * 64 + cA * 16 + q * 4;
    if (co0 >= Cout) continue;
    floatx4 bb = *(const floatx4*)(bias + co0);
    int a = is_cls ? (co0 / 80) : (co0 >> 2);
    int col0 = is_cls ? (co0 - a * 80) : 80;
#pragma unroll
    for (int rr = 0; rr < 8; rr++) {
      int h = h0 + wv * 8 + rr;
      int w_ = w0 + n16;
      if (h < H && w_ < W) {
        size_t ridx = (size_t)RB[l] + ((size_t)h * W + w_) * 9 + a;
        floatx4 v;
#pragma unroll
        for (int rg = 0; rg < 4; rg++) v[rg] = acc[cA][rr][rg] + bb[rg];
        *(floatx4*)(out + ((size_t)n * 120087 + ridx) * 84 + col0) = v;
      }
    }
  }
}

extern "C" void kernel_launch(void* const* d_in, const int* in_sizes, int n_in,
                              void* d_out, int out_size, void* d_ws,
                              size_t ws_size, hipStream_t stream) {
  // ws layout (bytes):
  //   bufB [0, 28964864)    (X0 aliased to bufB planes 2,3: dead after layer 1)
  //   X0   [14482432, 28964864)
  //   bufA [28964864, 57929728)
  //   tower blobs 8 x 1179648 at 57929728 (cls0..3, box0..3)
  //   cls final blob 3538944 at 67366912; box final blob 294912 at 70905856
  char* ws = (char*)d_ws;
  unsigned short* bufB = (unsigned short*)(ws);
  unsigned short* X0 = (unsigned short*)(ws + 14482432);
  unsigned short* bufA = (unsigned short*)(ws + 28964864);
  unsigned short* tb[8];
  for (int i = 0; i < 8; i++)
    tb[i] = (unsigned short*)(ws + 57929728 + (size_t)i * 1179648);
  unsigned short* fb_cls = (unsigned short*)(ws + 67366912);
  unsigned short* fb_box = (unsigned short*)(ws + 70905856);

  float* out = (float*)d_out;

  PrepArgs pa;
  for (int i = 0; i < 5; i++) pa.f[i] = (const float*)d_in[i];
  for (int i = 0; i < 4; i++) {
    pa.w[i] = (const float*)d_in[5 + 2 * i];       // cls_w0..3
    pa.w[4 + i] = (const float*)d_in[13 + 2 * i];  // box_w0..3
    pa.wdst[i] = tb[i];
    pa.wdst[4 + i] = tb[4 + i];
    pa.cout[i] = pa.cout[4 + i] = 256;
  }
  pa.w[8] = (const float*)d_in[21]; pa.wdst[8] = fb_cls; pa.cout[8] = 720;
  pa.w[9] = (const float*)d_in[23]; pa.wdst[9] = fb_box; pa.cout[9] = 36;
  // padded-co block counts: towers 256 each, cls 768, box 64
  int off = 0;
  for (int i = 0; i < 8; i++) { pa.wblk_off[i] = off; off += 256; }
  pa.wblk_off[8] = off; off += 768;
  pa.wblk_off[9] = off; off += 64;
  pa.wblk_off[10] = off;  // 2880
  pa.x0 = X0;
  pa.bufA = bufA;
  pa.bufB = bufB;

  prep<<<dim3(4770), 256, 0, stream>>>(pa);

  const float *cls_b[4], *box_b[4];
  for (int i = 0; i < 4; i++) {
    cls_b[i] = (const float*)d_in[6 + 2 * i];
    box_b[i] = (const float*)d_in[14 + 2 * i];
  }

  dim3 gt(40, 4, 4);
  conv_tower_mfma<<<gt, 256, 0, stream>>>(X0, bufA, tb[0], tb[4], cls_b[0],
                                          box_b[0], LVLTOT, 0);
  conv_tower_mfma<<<gt, 256, 0, stream>>>(bufA, bufB, tb[1], tb[5], cls_b[1],
                                          box_b[1], 2 * LVLTOT, LVLTOT);
  conv_tower_mfma<<<gt, 256, 0, stream>>>(bufB, bufA, tb[2], tb[6], cls_b[2],
                                          box_b[2], 2 * LVLTOT, LVLTOT);
  conv_tower_mfma<<<gt, 256, 0, stream>>>(bufA, bufB, tb[3], tb[7], cls_b[3],
                                          box_b[3], 2 * LVLTOT, LVLTOT);

  conv_final_mfma<<<dim3(40, 13, 2), 256, 0, stream>>>(
      bufB, out, fb_cls, fb_box, (const float*)d_in[22], (const float*)d_in[24]);
}

// Round 6
// 632.226 us; speedup vs baseline: 1.2147x; 1.2147x over previous
//
#include <hip/hip_runtime.h>

// RetinaNet head via bf16 MFMA implicit-GEMM (16x16x32) — R7 structure.
// Activations: padded NHWC bf16 [plane][(H+2)(W+2)][256], zero borders.
// R7 = R1's exact compute/sync structure (single-buffered LDS, 2 barriers
// per ci-chunk, 2 blocks/CU — the measured structure ceiling ~40% MfmaUtil
// that R2-R6 schedule/geometry variants all failed to move) with 14% LESS
// padded FLOP: row-pair segment tiling. Segment = 2 output rows x 16 cols;
// 487 segments over 5 levels (50x7+25x4+13x2+7+4); block = 8 segments
// (61 blocks), 4 waves, wave = 64co x 64px = 2 segments. Padded px
// 15584 vs 13343 real (1.168x) vs R1's 18176 (1.362x).
// X LDS: [q4][seg8][row4][col18] 16B units = 36864B; W unchanged 36864B;
// total 73728B -> 2 blocks/CU. Per chunk/wave: 24 B + 36 A ds_read_b128
// (quarter-wave-contiguous, bank-clean like R1) feed 144 MFMA.
// W blob layout (R1's): [cb][chunk32][tap][q4][co64][8ci].

typedef __attribute__((ext_vector_type(8))) short short8;
typedef __attribute__((ext_vector_type(4))) float floatx4;

#define LVLTOT 14143  // sum of padded (H+2)(W+2) over 5 levels

__device__ __forceinline__ unsigned short f2bf(float f) {
  unsigned int u = __float_as_uint(f);
  unsigned int r = (u + 0x7fffu + ((u >> 16) & 1u)) >> 16;
  return (unsigned short)r;
}

__device__ __forceinline__ void gload_lds16(const void* g, void* l) {
  __builtin_amdgcn_global_load_lds(
      (const __attribute__((address_space(1))) unsigned int*)g,
      (__attribute__((address_space(3))) unsigned int*)l, 16, 0, 0);
}

// ================= fused prep: xprep + wprep + border zero =================
// blocks [0,1090): xprep strips; [1090,3970): wprep (one co per block);
// [3970,4770): border zeroing (exact enumeration).  (unchanged from R1)
struct PrepArgs {
  const float* f[5];
  const float* w[10];
  unsigned short* wdst[10];
  int wblk_off[11];
  int cout[10];
  unsigned short* x0;
  unsigned short* bufA;
  unsigned short* bufB;
};

__global__ __launch_bounds__(256) void prep(PrepArgs A) {
  static const int Ht[5] = {100, 50, 25, 13, 7};
  static const int Wpt[5] = {102, 52, 27, 15, 9};
  static const int LOFFt[5] = {0, 10404, 13108, 13837, 14062};
  __shared__ float ts[32][33];
  const int bid = blockIdx.x;
  const int t = threadIdx.x;

  if (bid < 1090) {
    // ---- xprep: one 32-px row-strip, all 256 ch, one n ----
    int sid = bid % 545, n = bid / 545;
    int l, h, wb;
    if (sid < 400)      { l = 0; h = sid >> 2; wb = sid & 3; }
    else if (sid < 500) { l = 1; h = (sid - 400) >> 1; wb = (sid - 400) & 1; }
    else if (sid < 525) { l = 2; h = sid - 500; wb = 0; }
    else if (sid < 538) { l = 3; h = sid - 525; wb = 0; }
    else                { l = 4; h = sid - 538; wb = 0; }
    const float* f = A.f[l];
    int H = Ht[l], W = H, Wp = Wpt[l], loff = LOFFt[l];
    int w0 = wb * 32;
    for (int s = 0; s < 8; s++) {
      int ch0 = s * 32;
      __syncthreads();
#pragma unroll
      for (int r4 = 0; r4 < 4; r4++) {
        int ch = ch0 + (t >> 5) + r4 * 8;
        int px = w0 + (t & 31);
        float v = 0.f;
        if (px < W) v = f[(((size_t)n * 256 + ch) * H + h) * W + px];
        ts[(t >> 5) + r4 * 8][t & 31] = v;
      }
      __syncthreads();
      int pxl = t >> 3, c4 = t & 7;
      if (w0 + pxl < W) {
        unsigned short pk[4];
#pragma unroll
        for (int k = 0; k < 4; k++) pk[k] = f2bf(ts[c4 * 4 + k][pxl]);
        *(unsigned long long*)(A.x0 +
            ((size_t)n * LVLTOT + loff + (size_t)(h + 1) * Wp + (w0 + pxl + 1)) *
                256 + ch0 + c4 * 4) = *(unsigned long long*)pk;
      }
    }
    return;
  }

  if (bid < 3970) {
    // ---- wprep: block = one padded co of one tensor; thread = ci ----
    // Layout: [cb][chunk(ci>>5)][tap][qd][co64][8]
    int b2 = bid - 1090;
    int tix = 0;
    while (b2 >= A.wblk_off[tix + 1]) tix++;
    int co = b2 - A.wblk_off[tix];
    int ci = t;
    bool valid = co < A.cout[tix];
    const float* w = A.w[tix];
    unsigned short* dst = A.wdst[tix];
    int cb = co >> 6, col = co & 63, chk = ci >> 5, qd = (ci >> 3) & 3, j = ci & 7;
#pragma unroll
    for (int tap = 0; tap < 9; tap++) {
      float v = valid ? w[((size_t)co * 256 + ci) * 9 + tap] : 0.f;
      dst[((((size_t)(cb * 8 + chk) * 9 + tap) * 4 + qd) * 64 + col) * 8 + j] =
          f2bf(v);
    }
    return;
  }

  // ---- border zero: items = 800 border px x 32 octs per plane ----
  {
    static const int BCUM[6] = {0, 404, 608, 712, 768, 800};
    int b3 = bid - 3970;             // [0,800): plane = b3/100
    int plane = b3 / 100;
    int item = (b3 % 100) * 256 + t; // [0,25600)
    int pxi = item >> 5, oct = item & 31;
    if (pxi >= 800) return;
    int l = 0;
    while (pxi >= BCUM[l + 1]) l++;
    int j = pxi - BCUM[l];
    int Wp = Wpt[l];
    int r, c;
    if (j < Wp)            { r = 0; c = j; }
    else if (j < 2 * Wp)   { r = Wp - 1; c = j - Wp; }
    else { int k = j - 2 * Wp; r = 1 + (k >> 1); c = (k & 1) ? Wp - 1 : 0; }
    size_t px = (size_t)LOFFt[l] + (size_t)r * Wp + c;
    unsigned short* base = (plane < 4)
                               ? (A.bufA + (size_t)plane * LVLTOT * 256)
                               : (A.bufB + (size_t)(plane - 4) * LVLTOT * 256);
    floatx4 z;
    z[0] = z[1] = z[2] = z[3] = 0.f;
    *(floatx4*)(base + px * 256 + oct * 8) = z;
  }
}

// ---- segment decode: seg s -> level, top output row h0 (=2*pair), w0 ----
// Segments per level: l0 50x7=350, l1 25x4=100, l2 13x2=26, l3 7, l4 4.
__device__ __forceinline__ void decode_seg(int s, int& l, int& h0, int& w0,
                                           int& H, int& Wp, int& loff) {
  if (s < 350)      { l = 0; int hp = s / 7; w0 = (s - hp * 7) * 16; h0 = hp * 2;
                      H = 100; Wp = 102; loff = 0; }
  else if (s < 450) { l = 1; int r = s - 350; h0 = (r >> 2) * 2; w0 = (r & 3) * 16;
                      H = 50; Wp = 52; loff = 10404; }
  else if (s < 476) { l = 2; int r = s - 450; h0 = (r >> 1) * 2; w0 = (r & 1) * 16;
                      H = 25; Wp = 27; loff = 13108; }
  else if (s < 483) { l = 3; h0 = (s - 476) * 2; w0 = 0; H = 13; Wp = 15;
                      loff = 13837; }
  else              { l = 4; h0 = (s - 483) * 2; w0 = 0; H = 7; Wp = 9;
                      loff = 14062; }
}

// ---- per-thread X staging source offsets (plane-relative shorts, ci=0) ----
// 2304 16B-units = [q4][seg8][row4][col18]; unit u = k*256 + t; dest linear.
#define CONV_XPRE()                                                            \
  int xsrc[9];                                                                 \
  _Pragma("unroll") for (int k = 0; k < 9; k++) {                              \
    int u = k * 256 + t;                                                       \
    int qq = u / 576, rem = u - qq * 576;                                      \
    int sl8 = rem / 72, rm2 = rem - sl8 * 72;                                  \
    int r4 = rm2 / 18, c18 = rm2 - r4 * 18;                                    \
    int sg = blockIdx.x * 8 + sl8; if (sg > 486) sg = 486;                     \
    int l_, h0_, w0_, H_, Wp_, lo_;                                            \
    decode_seg(sg, l_, h0_, w0_, H_, Wp_, lo_);                                \
    int prow = h0_ + r4; if (prow > H_ + 1) prow = H_ + 1;                     \
    int pcol = w0_ + c18; if (pcol > Wp_ - 1) pcol = Wp_ - 1;                  \
    xsrc[k] = (lo_ + prow * Wp_ + pcol) * 256 + qq * 8;                        \
  }

// ---- K-loop body (R1 sync structure; needs: t, lane, wv, q, n16, xsrc,
//      lds_w, lds_x, acc[4][4]) ----
#define CONV_MAIN_LOOP(INP, WBLOB, CB)                                         \
  {                                                                            \
    _Pragma("unroll 1") for (int ch = 0; ch < 8; ch++) {                       \
      if (ch) __syncthreads();                                                 \
      const unsigned short* wsrc = (WBLOB) + ((size_t)((CB)*8 + ch)) * 18432;  \
      _Pragma("unroll") for (int i = 0; i < 9; i++)                            \
        gload_lds16(wsrc + i * 2048 + wv * 512 + lane * 8,                     \
                    lds_w + i * 2048 + wv * 512);                              \
      _Pragma("unroll") for (int k = 0; k < 9; k++)                            \
        gload_lds16((INP) + xsrc[k] + ch * 32,                                 \
                    lds_x + (size_t)(k * 256 + wv * 64) * 8);                  \
      __syncthreads();                                                         \
      const short8* xw = (const short8*)lds_w;                                 \
      const short8* xx = (const short8*)lds_x;                                 \
      _Pragma("unroll") for (int tdx = 0; tdx < 3; tdx++) {                    \
        short8 bfr[2][4];                                                      \
        _Pragma("unroll") for (int sb = 0; sb < 2; sb++)                       \
          _Pragma("unroll") for (int r = 0; r < 4; r++)                        \
            bfr[sb][r] =                                                       \
                xx[q * 576 + (wv * 2 + sb) * 72 + r * 18 + tdx + n16];         \
        _Pragma("unroll") for (int tdy = 0; tdy < 3; tdy++) {                  \
          const int tap = tdy * 3 + tdx;                                       \
          _Pragma("unroll") for (int cc = 0; cc < 4; cc++) {                   \
            short8 afr = xw[(tap * 4 + q) * 64 + cc * 16 + n16];               \
            _Pragma("unroll") for (int rg = 0; rg < 4; rg++)                   \
              acc[cc][rg] = __builtin_amdgcn_mfma_f32_16x16x32_bf16(           \
                  afr, bfr[rg >> 1][(rg & 1) + tdy], acc[cc][rg], 0, 0, 0);    \
          }                                                                    \
        }                                                                      \
      }                                                                        \
    }                                                                          \
  }

// ---- tower conv layer (bf16 in -> bf16 out, +bias, ReLU) ----
__global__ __launch_bounds__(256, 2) void conv_tower_mfma(
    const unsigned short* __restrict__ xin, unsigned short* __restrict__ xout,
    const unsigned short* __restrict__ wblob_cls,
    const unsigned short* __restrict__ wblob_box,
    const float* __restrict__ bias_cls, const float* __restrict__ bias_box,
    int in_n_stride, int in_tw_stride) {
  __shared__ __align__(16) unsigned short lds_w[18432];
  __shared__ __align__(16) unsigned short lds_x[18432];
  const int t = threadIdx.x, lane = t & 63, wv = t >> 6;
  const int q = lane >> 4, n16 = lane & 15;
  const int cb = blockIdx.y;
  const int n = blockIdx.z >> 1, tw = blockIdx.z & 1;
  const unsigned short* wblob = tw ? wblob_box : wblob_cls;
  const float* bias = tw ? bias_box : bias_cls;
  const unsigned short* inp =
      xin + ((size_t)n * in_n_stride + (size_t)tw * in_tw_stride) * 256;
  unsigned short* outp = xout + ((size_t)(n * 2 + tw) * LVLTOT) * 256;

  floatx4 acc[4][4];
#pragma unroll
  for (int i = 0; i < 4; i++)
#pragma unroll
    for (int jj = 0; jj < 4; jj++) acc[i][jj] = (floatx4){0.f, 0.f, 0.f, 0.f};

  CONV_XPRE()
  CONV_MAIN_LOOP(inp, wblob, cb)

  // epilogue: +bias, relu, bf16, store 4 consecutive channels (8B) per lane
#pragma unroll
  for (int rg = 0; rg < 4; rg++) {
    int sg = blockIdx.x * 8 + wv * 2 + (rg >> 1);
    if (sg > 486) sg = 486;
    int l_, h0_, w0_, H_, Wp_, lo_;
    decode_seg(sg, l_, h0_, w0_, H_, Wp_, lo_);
    int h = h0_ + (rg & 1);
    int w_ = w0_ + n16;
    if (h < H_ && w_ < H_) {  // levels are square: W == H
#pragma unroll
      for (int cc = 0; cc < 4; cc++) {
        floatx4 bb = *(const floatx4*)(bias + cb * 64 + cc * 16 + q * 4);
        unsigned short pk[4];
#pragma unroll
        for (int rgi = 0; rgi < 4; rgi++)
          pk[rgi] = f2bf(fmaxf(acc[cc][rg][rgi] + bb[rgi], 0.f));
        size_t base = ((size_t)lo_ + (size_t)(h + 1) * Wp_ + (w_ + 1)) * 256 +
                      cb * 64 + cc * 16 + q * 4;
        *(unsigned long long*)(outp + base) = *(unsigned long long*)pk;
      }
    }
  }
}

// ---- merged final conv (y<12: cls cb=y; y==12: box), permuted fp32 out ----
__global__ __launch_bounds__(256, 2) void conv_final_mfma(
    const unsigned short* __restrict__ xin, float* __restrict__ out,
    const unsigned short* __restrict__ wblob_cls,
    const unsigned short* __restrict__ wblob_box,
    const float* __restrict__ bias_cls, const float* __restrict__ bias_box) {
  __shared__ __align__(16) unsigned short lds_w[18432];
  __shared__ __align__(16) unsigned short lds_x[18432];
  const int t = threadIdx.x, lane = t & 63, wv = t >> 6;
  const int q = lane >> 4, n16 = lane & 15;
  const int yb = blockIdx.y;
  const bool is_cls = yb < 12;
  const int cb = is_cls ? yb : 0;
  const int tw = is_cls ? 0 : 1;
  const int Cout = is_cls ? 720 : 36;
  const unsigned short* wblob = is_cls ? wblob_cls : wblob_box;
  const float* bias = is_cls ? bias_cls : bias_box;
  const int n = blockIdx.z;
  const int RB[5] = {0, 90000, 112500, 118125, 119646};
  const unsigned short* inp = xin + ((size_t)(n * 2 + tw) * LVLTOT) * 256;

  floatx4 acc[4][4];
#pragma unroll
  for (int i = 0; i < 4; i++)
#pragma unroll
    for (int jj = 0; jj < 4; jj++) acc[i][jj] = (floatx4){0.f, 0.f, 0.f, 0.f};

  CONV_XPRE()
  CONV_MAIN_LOOP(inp, wblob, cb)

#pragma unroll
  for (int rg = 0; rg < 4; rg++) {
    int sg = blockIdx.x * 8 + wv * 2 + (rg >> 1);
    if (sg > 486) sg = 486;
    int l_, h0_, w0_, H_, Wp_, lo_;
    decode_seg(sg, l_, h0_, w0_, H_, Wp_, lo_);
    int h = h0_ + (rg & 1);
    int w_ = w0_ + n16;
    if (h < H_ && w_ < H_) {
      size_t ridx = (size_t)RB[l_] + ((size_t)h * H_ + w_) * 9;
#pragma unroll
      for (int cc = 0; cc < 4; cc++) {
        int co0 = cb * 64 + cc * 16 + q * 4;
        if (co0 >= Cout) continue;
        floatx4 bb = *(const floatx4*)(bias + co0);
        int a = is_cls ? (co0 / 80) : (co0 >> 2);
        int col0 = is_cls ? (co0 - a * 80) : 80;
        floatx4 v;
#pragma unroll
        for (int rgi = 0; rgi < 4; rgi++) v[rgi] = acc[cc][rg][rgi] + bb[rgi];
        *(floatx4*)(out + ((size_t)n * 120087 + ridx + a) * 84 + col0) = v;
      }
    }
  }
}

extern "C" void kernel_launch(void* const* d_in, const int* in_sizes, int n_in,
                              void* d_out, int out_size, void* d_ws,
                              size_t ws_size, hipStream_t stream) {
  // ws layout (bytes):
  //   bufB [0, 28964864)    (X0 aliased to bufB planes 2,3: dead after layer 1)
  //   X0   [14482432, 28964864)
  //   bufA [28964864, 57929728)
  //   tower blobs 8 x 1179648 at 57929728 (cls0..3, box0..3)
  //   cls final blob 3538944 at 67366912; box final blob 294912 at 70905856
  char* ws = (char*)d_ws;
  unsigned short* bufB = (unsigned short*)(ws);
  unsigned short* X0 = (unsigned short*)(ws + 14482432);
  unsigned short* bufA = (unsigned short*)(ws + 28964864);
  unsigned short* tb[8];
  for (int i = 0; i < 8; i++)
    tb[i] = (unsigned short*)(ws + 57929728 + (size_t)i * 1179648);
  unsigned short* fb_cls = (unsigned short*)(ws + 67366912);
  unsigned short* fb_box = (unsigned short*)(ws + 70905856);

  float* out = (float*)d_out;

  PrepArgs pa;
  for (int i = 0; i < 5; i++) pa.f[i] = (const float*)d_in[i];
  for (int i = 0; i < 4; i++) {
    pa.w[i] = (const float*)d_in[5 + 2 * i];       // cls_w0..3
    pa.w[4 + i] = (const float*)d_in[13 + 2 * i];  // box_w0..3
    pa.wdst[i] = tb[i];
    pa.wdst[4 + i] = tb[4 + i];
    pa.cout[i] = pa.cout[4 + i] = 256;
  }
  pa.w[8] = (const float*)d_in[21]; pa.wdst[8] = fb_cls; pa.cout[8] = 720;
  pa.w[9] = (const float*)d_in[23]; pa.wdst[9] = fb_box; pa.cout[9] = 36;
  // padded-co block counts: towers 256 each, cls 768, box 64
  int off = 0;
  for (int i = 0; i < 8; i++) { pa.wblk_off[i] = off; off += 256; }
  pa.wblk_off[8] = off; off += 768;
  pa.wblk_off[9] = off; off += 64;
  pa.wblk_off[10] = off;  // 2880
  pa.x0 = X0;
  pa.bufA = bufA;
  pa.bufB = bufB;

  prep<<<dim3(4770), 256, 0, stream>>>(pa);

  const float *cls_b[4], *box_b[4];
  for (int i = 0; i < 4; i++) {
    cls_b[i] = (const float*)d_in[6 + 2 * i];
    box_b[i] = (const float*)d_in[14 + 2 * i];
  }

  dim3 gt(61, 4, 4);
  conv_tower_mfma<<<gt, 256, 0, stream>>>(X0, bufA, tb[0], tb[4], cls_b[0],
                                          box_b[0], LVLTOT, 0);
  conv_tower_mfma<<<gt, 256, 0, stream>>>(bufA, bufB, tb[1], tb[5], cls_b[1],
                                          box_b[1], 2 * LVLTOT, LVLTOT);
  conv_tower_mfma<<<gt, 256, 0, stream>>>(bufB, bufA, tb[2], tb[6], cls_b[2],
                                          box_b[2], 2 * LVLTOT, LVLTOT);
  conv_tower_mfma<<<gt, 256, 0, stream>>>(bufA, bufB, tb[3], tb[7], cls_b[3],
                                          box_b[3], 2 * LVLTOT, LVLTOT);

  conv_final_mfma<<<dim3(61, 13, 2), 256, 0, stream>>>(
      bufB, out, fb_cls, fb_box, (const float*)d_in[22], (const float*)d_in[24]);
}

// Round 7
// 608.041 us; speedup vs baseline: 1.2630x; 1.0398x over previous
//
#include <hip/hip_runtime.h>

// RetinaNet head via bf16 MFMA implicit-GEMM (16x16x32) — R8 structure.
// R8 = R7 (row-pair segment tiling, R1 sync core) + XCD cb-stacking swizzle:
// flat grid, physical block p -> xcd = p&7, j = p>>3; within an XCD the
// j-sequence enumerates (tile-plane, cb) with cb FASTEST, so all cb-blocks
// that re-read the same X halo are co-resident on one XCD and adjacent in
// dispatch order -> X staged from HBM once, then L2-hit for the other
// 12 (final) / 3 (tower) sibling blocks. Compute core unchanged from R7.
// Final: 122 tile-planes, XCD<2 get 16 else 15; grid 8*13*16=1664 (tail exits).
// Tower: 244 tile-planes, XCD<4 get 31 else 30; grid 8*4*31=992 (tail exits).

typedef __attribute__((ext_vector_type(8))) short short8;
typedef __attribute__((ext_vector_type(4))) float floatx4;

#define LVLTOT 14143  // sum of padded (H+2)(W+2) over 5 levels

__device__ __forceinline__ unsigned short f2bf(float f) {
  unsigned int u = __float_as_uint(f);
  unsigned int r = (u + 0x7fffu + ((u >> 16) & 1u)) >> 16;
  return (unsigned short)r;
}

__device__ __forceinline__ void gload_lds16(const void* g, void* l) {
  __builtin_amdgcn_global_load_lds(
      (const __attribute__((address_space(1))) unsigned int*)g,
      (__attribute__((address_space(3))) unsigned int*)l, 16, 0, 0);
}

// ================= fused prep: xprep + wprep + border zero =================
// (unchanged from R7)
struct PrepArgs {
  const float* f[5];
  const float* w[10];
  unsigned short* wdst[10];
  int wblk_off[11];
  int cout[10];
  unsigned short* x0;
  unsigned short* bufA;
  unsigned short* bufB;
};

__global__ __launch_bounds__(256) void prep(PrepArgs A) {
  static const int Ht[5] = {100, 50, 25, 13, 7};
  static const int Wpt[5] = {102, 52, 27, 15, 9};
  static const int LOFFt[5] = {0, 10404, 13108, 13837, 14062};
  __shared__ float ts[32][33];
  const int bid = blockIdx.x;
  const int t = threadIdx.x;

  if (bid < 1090) {
    // ---- xprep: one 32-px row-strip, all 256 ch, one n ----
    int sid = bid % 545, n = bid / 545;
    int l, h, wb;
    if (sid < 400)      { l = 0; h = sid >> 2; wb = sid & 3; }
    else if (sid < 500) { l = 1; h = (sid - 400) >> 1; wb = (sid - 400) & 1; }
    else if (sid < 525) { l = 2; h = sid - 500; wb = 0; }
    else if (sid < 538) { l = 3; h = sid - 525; wb = 0; }
    else                { l = 4; h = sid - 538; wb = 0; }
    const float* f = A.f[l];
    int H = Ht[l], W = H, Wp = Wpt[l], loff = LOFFt[l];
    int w0 = wb * 32;
    for (int s = 0; s < 8; s++) {
      int ch0 = s * 32;
      __syncthreads();
#pragma unroll
      for (int r4 = 0; r4 < 4; r4++) {
        int ch = ch0 + (t >> 5) + r4 * 8;
        int px = w0 + (t & 31);
        float v = 0.f;
        if (px < W) v = f[(((size_t)n * 256 + ch) * H + h) * W + px];
        ts[(t >> 5) + r4 * 8][t & 31] = v;
      }
      __syncthreads();
      int pxl = t >> 3, c4 = t & 7;
      if (w0 + pxl < W) {
        unsigned short pk[4];
#pragma unroll
        for (int k = 0; k < 4; k++) pk[k] = f2bf(ts[c4 * 4 + k][pxl]);
        *(unsigned long long*)(A.x0 +
            ((size_t)n * LVLTOT + loff + (size_t)(h + 1) * Wp + (w0 + pxl + 1)) *
                256 + ch0 + c4 * 4) = *(unsigned long long*)pk;
      }
    }
    return;
  }

  if (bid < 3970) {
    // ---- wprep: block = one padded co of one tensor; thread = ci ----
    // Layout: [cb][chunk(ci>>5)][tap][qd][co64][8]
    int b2 = bid - 1090;
    int tix = 0;
    while (b2 >= A.wblk_off[tix + 1]) tix++;
    int co = b2 - A.wblk_off[tix];
    int ci = t;
    bool valid = co < A.cout[tix];
    const float* w = A.w[tix];
    unsigned short* dst = A.wdst[tix];
    int cb = co >> 6, col = co & 63, chk = ci >> 5, qd = (ci >> 3) & 3, j = ci & 7;
#pragma unroll
    for (int tap = 0; tap < 9; tap++) {
      float v = valid ? w[((size_t)co * 256 + ci) * 9 + tap] : 0.f;
      dst[((((size_t)(cb * 8 + chk) * 9 + tap) * 4 + qd) * 64 + col) * 8 + j] =
          f2bf(v);
    }
    return;
  }

  // ---- border zero: items = 800 border px x 32 octs per plane ----
  {
    static const int BCUM[6] = {0, 404, 608, 712, 768, 800};
    int b3 = bid - 3970;             // [0,800): plane = b3/100
    int plane = b3 / 100;
    int item = (b3 % 100) * 256 + t; // [0,25600)
    int pxi = item >> 5, oct = item & 31;
    if (pxi >= 800) return;
    int l = 0;
    while (pxi >= BCUM[l + 1]) l++;
    int j = pxi - BCUM[l];
    int Wp = Wpt[l];
    int r, c;
    if (j < Wp)            { r = 0; c = j; }
    else if (j < 2 * Wp)   { r = Wp - 1; c = j - Wp; }
    else { int k = j - 2 * Wp; r = 1 + (k >> 1); c = (k & 1) ? Wp - 1 : 0; }
    size_t px = (size_t)LOFFt[l] + (size_t)r * Wp + c;
    unsigned short* base = (plane < 4)
                               ? (A.bufA + (size_t)plane * LVLTOT * 256)
                               : (A.bufB + (size_t)(plane - 4) * LVLTOT * 256);
    floatx4 z;
    z[0] = z[1] = z[2] = z[3] = 0.f;
    *(floatx4*)(base + px * 256 + oct * 8) = z;
  }
}

// ---- segment decode: seg s -> level, top output row h0 (=2*pair), w0 ----
// Segments per level: l0 50x7=350, l1 25x4=100, l2 13x2=26, l3 7, l4 4.
__device__ __forceinline__ void decode_seg(int s, int& l, int& h0, int& w0,
                                           int& H, int& Wp, int& loff) {
  if (s < 350)      { l = 0; int hp = s / 7; w0 = (s - hp * 7) * 16; h0 = hp * 2;
                      H = 100; Wp = 102; loff = 0; }
  else if (s < 450) { l = 1; int r = s - 350; h0 = (r >> 2) * 2; w0 = (r & 3) * 16;
                      H = 50; Wp = 52; loff = 10404; }
  else if (s < 476) { l = 2; int r = s - 450; h0 = (r >> 1) * 2; w0 = (r & 1) * 16;
                      H = 25; Wp = 27; loff = 13108; }
  else if (s < 483) { l = 3; h0 = (s - 476) * 2; w0 = 0; H = 13; Wp = 15;
                      loff = 13837; }
  else              { l = 4; h0 = (s - 483) * 2; w0 = 0; H = 7; Wp = 9;
                      loff = 14062; }
}

// ---- per-thread X staging source offsets (plane-relative shorts, ci=0) ----
// 2304 16B-units = [q4][seg8][row4][col18]; unit u = k*256 + t; dest linear.
// needs in scope: sblk (segment-block index [0,61))
#define CONV_XPRE()                                                            \
  int xsrc[9];                                                                 \
  _Pragma("unroll") for (int k = 0; k < 9; k++) {                              \
    int u = k * 256 + t;                                                       \
    int qq = u / 576, rem = u - qq * 576;                                      \
    int sl8 = rem / 72, rm2 = rem - sl8 * 72;                                  \
    int r4 = rm2 / 18, c18 = rm2 - r4 * 18;                                    \
    int sg = sblk * 8 + sl8; if (sg > 486) sg = 486;                           \
    int l_, h0_, w0_, H_, Wp_, lo_;                                            \
    decode_seg(sg, l_, h0_, w0_, H_, Wp_, lo_);                                \
    int prow = h0_ + r4; if (prow > H_ + 1) prow = H_ + 1;                     \
    int pcol = w0_ + c18; if (pcol > Wp_ - 1) pcol = Wp_ - 1;                  \
    xsrc[k] = (lo_ + prow * Wp_ + pcol) * 256 + qq * 8;                        \
  }

// ---- K-loop body (R1 sync structure; needs: t, lane, wv, q, n16, xsrc,
//      lds_w, lds_x, acc[4][4]) ----
#define CONV_MAIN_LOOP(INP, WBLOB, CB)                                         \
  {                                                                            \
    _Pragma("unroll 1") for (int ch = 0; ch < 8; ch++) {                       \
      if (ch) __syncthreads();                                                 \
      const unsigned short* wsrc = (WBLOB) + ((size_t)((CB)*8 + ch)) * 18432;  \
      _Pragma("unroll") for (int i = 0; i < 9; i++)                            \
        gload_lds16(wsrc + i * 2048 + wv * 512 + lane * 8,                     \
                    lds_w + i * 2048 + wv * 512);                              \
      _Pragma("unroll") for (int k = 0; k < 9; k++)                            \
        gload_lds16((INP) + xsrc[k] + ch * 32,                                 \
                    lds_x + (size_t)(k * 256 + wv * 64) * 8);                  \
      __syncthreads();                                                         \
      const short8* xw = (const short8*)lds_w;                                 \
      const short8* xx = (const short8*)lds_x;                                 \
      _Pragma("unroll") for (int tdx = 0; tdx < 3; tdx++) {                    \
        short8 bfr[2][4];                                                      \
        _Pragma("unroll") for (int sb = 0; sb < 2; sb++)                       \
          _Pragma("unroll") for (int r = 0; r < 4; r++)                        \
            bfr[sb][r] =                                                       \
                xx[q * 576 + (wv * 2 + sb) * 72 + r * 18 + tdx + n16];         \
        _Pragma("unroll") for (int tdy = 0; tdy < 3; tdy++) {                  \
          const int tap = tdy * 3 + tdx;                                       \
          _Pragma("unroll") for (int cc = 0; cc < 4; cc++) {                   \
            short8 afr = xw[(tap * 4 + q) * 64 + cc * 16 + n16];               \
            _Pragma("unroll") for (int rg = 0; rg < 4; rg++)                   \
              acc[cc][rg] = __builtin_amdgcn_mfma_f32_16x16x32_bf16(           \
                  afr, bfr[rg >> 1][(rg & 1) + tdy], acc[cc][rg], 0, 0, 0);    \
          }                                                                    \
        }                                                                      \
      }                                                                        \
    }                                                                          \
  }

// ---- tower conv layer (bf16 in -> bf16 out, +bias, ReLU) ----
// XCD swizzle: p -> xcd=p&7, j=p>>3; cnt = 31 (xcd<4) else 30;
// j = tlw*4 + cb (cb fastest); tl = tlw*8 + xcd in [0,244);
// sblk = tl % 61, plane = tl / 61.
__global__ __launch_bounds__(256, 2) void conv_tower_mfma(
    const unsigned short* __restrict__ xin, unsigned short* __restrict__ xout,
    const unsigned short* __restrict__ wblob_cls,
    const unsigned short* __restrict__ wblob_box,
    const float* __restrict__ bias_cls, const float* __restrict__ bias_box,
    int in_n_stride, int in_tw_stride) {
  const int p = blockIdx.x;
  const int xcd = p & 7, jj = p >> 3;
  const int cnt = (xcd < 4) ? 31 : 30;
  if (jj >= 4 * cnt) return;
  const int tlw = jj >> 2, cb = jj & 3;
  const int tl = tlw * 8 + xcd;
  const int sblk = tl % 61;
  const int zpl = tl / 61;
  const int n = zpl >> 1, tw = zpl & 1;

  __shared__ __align__(16) unsigned short lds_w[18432];
  __shared__ __align__(16) unsigned short lds_x[18432];
  const int t = threadIdx.x, lane = t & 63, wv = t >> 6;
  const int q = lane >> 4, n16 = lane & 15;
  const unsigned short* wblob = tw ? wblob_box : wblob_cls;
  const float* bias = tw ? bias_box : bias_cls;
  const unsigned short* inp =
      xin + ((size_t)n * in_n_stride + (size_t)tw * in_tw_stride) * 256;
  unsigned short* outp = xout + ((size_t)(n * 2 + tw) * LVLTOT) * 256;

  floatx4 acc[4][4];
#pragma unroll
  for (int i = 0; i < 4; i++)
#pragma unroll
    for (int jx = 0; jx < 4; jx++) acc[i][jx] = (floatx4){0.f, 0.f, 0.f, 0.f};

  CONV_XPRE()
  CONV_MAIN_LOOP(inp, wblob, cb)

  // epilogue: +bias, relu, bf16, store 4 consecutive channels (8B) per lane
#pragma unroll
  for (int rg = 0; rg < 4; rg++) {
    int sg = sblk * 8 + wv * 2 + (rg >> 1);
    if (sg > 486) sg = 486;
    int l_, h0_, w0_, H_, Wp_, lo_;
    decode_seg(sg, l_, h0_, w0_, H_, Wp_, lo_);
    int h = h0_ + (rg & 1);
    int w_ = w0_ + n16;
    if (h < H_ && w_ < H_) {  // levels are square: W == H
#pragma unroll
      for (int cc = 0; cc < 4; cc++) {
        floatx4 bb = *(const floatx4*)(bias + cb * 64 + cc * 16 + q * 4);
        unsigned short pk[4];
#pragma unroll
        for (int rgi = 0; rgi < 4; rgi++)
          pk[rgi] = f2bf(fmaxf(acc[cc][rg][rgi] + bb[rgi], 0.f));
        size_t base = ((size_t)lo_ + (size_t)(h + 1) * Wp_ + (w_ + 1)) * 256 +
                      cb * 64 + cc * 16 + q * 4;
        *(unsigned long long*)(outp + base) = *(unsigned long long*)pk;
      }
    }
  }
}

// ---- merged final conv (yb<12: cls cb=yb; yb==12: box), permuted fp32 out --
// XCD swizzle: p -> xcd=p&7, j=p>>3; cnt = 16 (xcd<2) else 15;
// j = tlw*13 + yb (yb fastest); tl = tlw*8 + xcd in [0,122);
// sblk = tl % 61, n = tl / 61.
__global__ __launch_bounds__(256, 2) void conv_final_mfma(
    const unsigned short* __restrict__ xin, float* __restrict__ out,
    const unsigned short* __restrict__ wblob_cls,
    const unsigned short* __restrict__ wblob_box,
    const float* __restrict__ bias_cls, const float* __restrict__ bias_box) {
  const int p = blockIdx.x;
  const int xcd = p & 7, jj = p >> 3;
  const int cnt = (xcd < 2) ? 16 : 15;
  if (jj >= 13 * cnt) return;
  const int tlw = jj / 13, yb = jj - tlw * 13;
  const int tl = tlw * 8 + xcd;
  const int sblk = tl % 61;
  const int n = tl / 61;

  __shared__ __align__(16) unsigned short lds_w[18432];
  __shared__ __align__(16) unsigned short lds_x[18432];
  const int t = threadIdx.x, lane = t & 63, wv = t >> 6;
  const int q = lane >> 4, n16 = lane & 15;
  const bool is_cls = yb < 12;
  const int cb = is_cls ? yb : 0;
  const int tw = is_cls ? 0 : 1;
  const int Cout = is_cls ? 720 : 36;
  const unsigned short* wblob = is_cls ? wblob_cls : wblob_box;
  const float* bias = is_cls ? bias_cls : bias_box;
  const int RB[5] = {0, 90000, 112500, 118125, 119646};
  const unsigned short* inp = xin + ((size_t)(n * 2 + tw) * LVLTOT) * 256;

  floatx4 acc[4][4];
#pragma unroll
  for (int i = 0; i < 4; i++)
#pragma unroll
    for (int jx = 0; jx < 4; jx++) acc[i][jx] = (floatx4){0.f, 0.f, 0.f, 0.f};

  CONV_XPRE()
  CONV_MAIN_LOOP(inp, wblob, cb)

#pragma unroll
  for (int rg = 0; rg < 4; rg++) {
    int sg = sblk * 8 + wv * 2 + (rg >> 1);
    if (sg > 486) sg = 486;
    int l_, h0_, w0_, H_, Wp_, lo_;
    decode_seg(sg, l_, h0_, w0_, H_, Wp_, lo_);
    int h = h0_ + (rg & 1);
    int w_ = w0_ + n16;
    if (h < H_ && w_ < H_) {
      size_t ridx = (size_t)RB[l_] + ((size_t)h * H_ + w_) * 9;
#pragma unroll
      for (int cc = 0; cc < 4; cc++) {
        int co0 = cb * 64 + cc * 16 + q * 4;
        if (co0 >= Cout) continue;
        floatx4 bb = *(const floatx4*)(bias + co0);
        int a = is_cls ? (co0 / 80) : (co0 >> 2);
        int col0 = is_cls ? (co0 - a * 80) : 80;
        floatx4 v;
#pragma unroll
        for (int rgi = 0; rgi < 4; rgi++) v[rgi] = acc[cc][rg][rgi] + bb[rgi];
        *(floatx4*)(out + ((size_t)n * 120087 + ridx + a) * 84 + col0) = v;
      }
    }
  }
}

extern "C" void kernel_launch(void* const* d_in, const int* in_sizes, int n_in,
                              void* d_out, int out_size, void* d_ws,
                              size_t ws_size, hipStream_t stream) {
  // ws layout (bytes):
  //   bufB [0, 28964864)    (X0 aliased to bufB planes 2,3: dead after layer 1)
  //   X0   [14482432, 28964864)
  //   bufA [28964864, 57929728)
  //   tower blobs 8 x 1179648 at 57929728 (cls0..3, box0..3)
  //   cls final blob 3538944 at 67366912; box final blob 294912 at 70905856
  char* ws = (char*)d_ws;
  unsigned short* bufB = (unsigned short*)(ws);
  unsigned short* X0 = (unsigned short*)(ws + 14482432);
  unsigned short* bufA = (unsigned short*)(ws + 28964864);
  unsigned short* tb[8];
  for (int i = 0; i < 8; i++)
    tb[i] = (unsigned short*)(ws + 57929728 + (size_t)i * 1179648);
  unsigned short* fb_cls = (unsigned short*)(ws + 67366912);
  unsigned short* fb_box = (unsigned short*)(ws + 70905856);

  float* out = (float*)d_out;

  PrepArgs pa;
  for (int i = 0; i < 5; i++) pa.f[i] = (const float*)d_in[i];
  for (int i = 0; i < 4; i++) {
    pa.w[i] = (const float*)d_in[5 + 2 * i];       // cls_w0..3
    pa.w[4 + i] = (const float*)d_in[13 + 2 * i];  // box_w0..3
    pa.wdst[i] = tb[i];
    pa.wdst[4 + i] = tb[4 + i];
    pa.cout[i] = pa.cout[4 + i] = 256;
  }
  pa.w[8] = (const float*)d_in[21]; pa.wdst[8] = fb_cls; pa.cout[8] = 720;
  pa.w[9] = (const float*)d_in[23]; pa.wdst[9] = fb_box; pa.cout[9] = 36;
  // padded-co block counts: towers 256 each, cls 768, box 64
  int off = 0;
  for (int i = 0; i < 8; i++) { pa.wblk_off[i] = off; off += 256; }
  pa.wblk_off[8] = off; off += 768;
  pa.wblk_off[9] = off; off += 64;
  pa.wblk_off[10] = off;  // 2880
  pa.x0 = X0;
  pa.bufA = bufA;
  pa.bufB = bufB;

  prep<<<dim3(4770), 256, 0, stream>>>(pa);

  const float *cls_b[4], *box_b[4];
  for (int i = 0; i < 4; i++) {
    cls_b[i] = (const float*)d_in[6 + 2 * i];
    box_b[i] = (const float*)d_in[14 + 2 * i];
  }

  conv_tower_mfma<<<dim3(992), 256, 0, stream>>>(X0, bufA, tb[0], tb[4],
                                                 cls_b[0], box_b[0], LVLTOT, 0);
  conv_tower_mfma<<<dim3(992), 256, 0, stream>>>(
      bufA, bufB, tb[1], tb[5], cls_b[1], box_b[1], 2 * LVLTOT, LVLTOT);
  conv_tower_mfma<<<dim3(992), 256, 0, stream>>>(
      bufB, bufA, tb[2], tb[6], cls_b[2], box_b[2], 2 * LVLTOT, LVLTOT);
  conv_tower_mfma<<<dim3(992), 256, 0, stream>>>(
      bufA, bufB, tb[3], tb[7], cls_b[3], box_b[3], 2 * LVLTOT, LVLTOT);

  conv_final_mfma<<<dim3(1664), 256, 0, stream>>>(
      bufB, out, fb_cls, fb_box, (const float*)d_in[22], (const float*)d_in[24]);
}